// Round 6
// baseline (106.400 us; speedup 1.0000x reference)
//
#include <hip/hip_runtime.h>

typedef __attribute__((ext_vector_type(2))) float f32x2;

#define W 4096
#define H 4096
#define NT 256
#define NW 4                     // waves per block (fully independent)
#define WCOLS 128                // columns per wave (64 lanes x 2)
#define SR 32                    // output rows per wave strip
#define GROUP 4                  // rows staged per pipeline step
#define NSTAGE (SR + 14)         // 46 staged rows contribute
#define NG 12                    // 12 groups of 4
#define LW (WCOLS + 16)          // 144 floats per staged row (8-col halo each side)
#define RAD 7
#define PEND 18                  // 15 + GROUP - 1

__global__ __launch_bounds__(NT, 4) void multibox_kernel(
    const float* __restrict__ x, const float* __restrict__ base,
    float* __restrict__ out)
{
    // per-wave private staging: no __syncthreads anywhere
    __shared__ float buf[NW][2][GROUP][LW];   // 18,432 B

    const int t  = threadIdx.x;
    const int w  = t >> 6;                    // wave id
    const int l  = t & 63;                    // lane
    const int c0 = blockIdx.x * WCOLS;        // wave's column panel
    const int i0 = (blockIdx.y * NW + w) * SR;// wave's row strip

    const float w3  = 1.f/(7.f*9.f);
    const float w5  = 1.f/(7.f*25.f);
    const float w7  = 1.f/(7.f*49.f);
    const float w9  = 1.f/(7.f*81.f);
    const float w11 = 1.f/(7.f*121.f);
    const float w13 = 1.f/(7.f*169.f);
    const float w15 = 1.f/(7.f*225.f);

    auto ld2 = [&](const float* __restrict__ rowp, int c) -> f32x2 {
        if (c >= 0 && c <= W - 2) return *(const f32x2*)(rowp + c);
        f32x2 v;
        v.x = rowp[min(max(c    , 0), W - 1)];
        v.y = rowp[min(max(c + 1, 0), W - 1)];
        return v;
    };

    f32x2 mreg[GROUP];           // main 128-col chunk (all lanes)
    f32x2 hreg[GROUP];           // 16-col halo chunk (lanes 0..7)

    auto load_group = [&](int g) {
        const int rb = i0 - RAD + g * GROUP;
#pragma unroll
        for (int rr = 0; rr < GROUP; ++rr) {
            const int rc = min(max(rb + rr, 0), H - 1);
            const float* rp = x + (size_t)rc * W;
            mreg[rr] = ld2(rp, c0 - 8 + 2 * l);
            if (l < 8) hreg[rr] = ld2(rp, c0 + 120 + 2 * l);
        }
    };

    auto write_group = [&](int b) {
#pragma unroll
        for (int rr = 0; rr < GROUP; ++rr) {
            *(f32x2*)&buf[w][b][rr][2 * l] = mreg[rr];
            if (l < 8) *(f32x2*)&buf[w][b][rr][128 + 2 * l] = hreg[rr];
        }
    };

    // Pnd[p] accumulates output row (i0 + 4g - 14 + p) before group g.
    // rr / p / d are compile-time (inner unrolls); g stays runtime.
    f32x2 Pnd[PEND];
#pragma unroll
    for (int q = 0; q < PEND; ++q) Pnd[q] = f32x2{0.f, 0.f};

    auto compute_group = [&](int b, int g) {
        // prefetch base rows for this group's emits (issued early, used late)
        f32x2 breg[GROUP];
#pragma unroll
        for (int p = 0; p < GROUP; ++p) {
            const int o_ofs = 4 * g - 14 + p;
            if (o_ofs >= 0 && o_ofs < SR)
                breg[p] = *(const f32x2*)(base + (size_t)(i0 + o_ofs) * W + c0 + 2 * l);
        }

#pragma unroll
        for (int rr = 0; rr < GROUP; ++rr) {
            if (g * GROUP + rr < NSTAGE) {
                const float* p = &buf[w][b][rr][2 * l];
                f32x2 q2[9];
#pragma unroll
                for (int i = 0; i < 9; ++i) q2[i] = *(const f32x2*)(p + 2 * i);

                auto PR = [&](int a) -> f32x2 {   // {row[2l-8+a], row[2l-7+a]}
                    if ((a & 1) == 0) return q2[a / 2];
                    f32x2 r;
                    r.x = q2[a / 2].y;
                    r.y = q2[a / 2 + 1].x;
                    return r;
                };

                f32x2 s3  = PR(7) + PR(8) + PR(9);
                f32x2 s5  = s3  + PR(6) + PR(10);
                f32x2 s7  = s5  + PR(5) + PR(11);
                f32x2 s9  = s7  + PR(4) + PR(12);
                f32x2 s11 = s9  + PR(3) + PR(13);
                f32x2 s13 = s11 + PR(2) + PR(14);
                f32x2 s15 = s13 + PR(1) + PR(15);

                f32x2 c7 = f32x2{w15, w15} * s15;
                f32x2 c6 = c7 + f32x2{w13, w13} * s13;
                f32x2 c5 = c6 + f32x2{w11, w11} * s11;
                f32x2 c4 = c5 + f32x2{w9 , w9 } * s9;
                f32x2 c3 = c4 + f32x2{w7 , w7 } * s7;
                f32x2 c2 = c3 + f32x2{w5 , w5 } * s5;
                f32x2 c1 = c2 + f32x2{w3 , w3 } * s3;

                Pnd[rr +  0] += c7; Pnd[rr +  1] += c6; Pnd[rr +  2] += c5;
                Pnd[rr +  3] += c4; Pnd[rr +  4] += c3; Pnd[rr +  5] += c2;
                Pnd[rr +  6] += c1; Pnd[rr +  7] += c1; Pnd[rr +  8] += c1;
                Pnd[rr +  9] += c2; Pnd[rr + 10] += c3; Pnd[rr + 11] += c4;
                Pnd[rr + 12] += c5; Pnd[rr + 13] += c6; Pnd[rr + 14] += c7;
            }
        }

        // emit completed rows: o_ofs = 4g - 14 + p
#pragma unroll
        for (int p = 0; p < GROUP; ++p) {
            const int o_ofs = 4 * g - 14 + p;
            if (o_ofs >= 0 && o_ofs < SR) {
                const size_t bi = (size_t)(i0 + o_ofs) * W + c0 + 2 * l;
                f32x2 ov = Pnd[p] * breg[p];
                *(f32x2*)(out + bi) = ov;
            }
        }

        // shift window by GROUP (static indices)
#pragma unroll
        for (int p = 0; p < PEND - GROUP; ++p) Pnd[p] = Pnd[p + GROUP];
#pragma unroll
        for (int p = PEND - GROUP; p < PEND; ++p) Pnd[p] = f32x2{0.f, 0.f};
    };

    // per-wave software pipeline; no barriers (wave-sequential LDS ordering)
    load_group(0);
    write_group(0);

    for (int g = 0; g < NG - 1; ++g) {
        load_group(g + 1);           // issue next group's global loads
        compute_group(g & 1, g);     // ds_read + VALU on current buffer
        write_group((g + 1) & 1);    // vmcnt wait lands here, not at a barrier
    }
    compute_group((NG - 1) & 1, NG - 1);
}

extern "C" void kernel_launch(void* const* d_in, const int* in_sizes, int n_in,
                              void* d_out, int out_size, void* d_ws, size_t ws_size,
                              hipStream_t stream) {
    const float* x    = (const float*)d_in[0];
    const float* base = (const float*)d_in[1];
    float* out        = (float*)d_out;

    dim3 grid(W / WCOLS, H / (NW * SR));   // (32, 32) = 1024 blocks, 4096 waves
    multibox_kernel<<<grid, dim3(NT), 0, stream>>>(x, base, out);
}